// Round 1
// baseline (764.457 us; speedup 1.0000x reference)
//
#include <hip/hip_runtime.h>
#include <hip/hip_bf16.h>

// Fused kernel for MDI_2422361555492 on gfx950.
// Math per row b:
//   pa,pb from Manhattan/cosine 2x2 adjacencies (closed form, row reductions)
//   x1_m = relu((pa*em+pb*ed)@Wgcn)+em ; x1_d = relu((pb*em+pa*ed)@Wgcn)+ed
//   t = x1@M (M=Wq@Wk^T); logits = (t.em, t.x1)/sqrt(C); attn=softmax
//   LA = (a0*x0 + a1*x1)@Wv ; ne = mLA*dLA ; out = sigmoid(relu(ne@W1).W2)
// MFMA mapping: C^T = W^T X^T with 32x32x16 bf16; X rows on lane&31 for both
// B-operand and C/D output; weight rows pre-permuted by P so GEMM outputs feed
// the next GEMM directly from registers (no LDS, no barriers).

typedef __attribute__((ext_vector_type(8))) short short8;
typedef __attribute__((ext_vector_type(16))) float f32x16;

__device__ __forceinline__ short bf16rne(float f) {
    unsigned int u = __builtin_bit_cast(unsigned int, f);
    u = (u + 0x7fffu + ((u >> 16) & 1u)) >> 16;
    return (short)u;
}
__device__ __forceinline__ float bf2f(short s) {
    unsigned int u = ((unsigned int)(unsigned short)s) << 16;
    return __builtin_bit_cast(float, u);
}

// Column-permutation induced by identifying GEMM-output slots with B-operand slots.
// slot: k = 16*c' + 8*h + j'  ->  actual column P(k)
__host__ __device__ __forceinline__ int P_perm(int k) {
    int c = k >> 4, t = k & 15, h = t >> 3, j = t & 7;
    return ((c >> 1) << 5) | ((c & 1) << 4) | ((j >> 2) << 3) | (h << 2) | (j & 3);
}

// ---- prologue 1: M = Wq @ Wk^T  (128x128, fp32) ----
__global__ void k_matmul_qkT(const float* __restrict__ Wq, const float* __restrict__ Wk,
                             float* __restrict__ M) {
    int idx = blockIdx.x * blockDim.x + threadIdx.x;   // 16384 threads
    int a = idx >> 7, b = idx & 127;
    float s = 0.f;
#pragma unroll 8
    for (int c = 0; c < 128; ++c) s += Wq[a * 128 + c] * Wk[b * 128 + c];
    M[idx] = s;
}

// ---- prologue 2: pack 6 matrices into P-permuted bf16 A-fragments ----
// layout: dst[(((mat*4+mb)*8 + c)*64 + lane)*8 + j]
//   value = bf16( W[P(16c + 8*(lane>>5) + j)][mb*32 + (lane&31)] )
__global__ void k_pack(const float* __restrict__ W0, const float* __restrict__ W1,
                       const float* __restrict__ W2, const float* __restrict__ W3,
                       const float* __restrict__ W4, const float* __restrict__ W5,
                       unsigned short* __restrict__ dst) {
    int idx = blockIdx.x * blockDim.x + threadIdx.x;   // 6*16384 threads
    int mat = idx >> 14;
    int r = idx & 16383;
    int mb = r >> 12;
    int c = (r >> 9) & 7;
    int l = (r >> 3) & 63;
    int j = r & 7;
    const float* W = mat == 0 ? W0 : mat == 1 ? W1 : mat == 2 ? W2
                   : mat == 3 ? W3 : mat == 4 ? W4 : W5;
    int k = 16 * c + 8 * (l >> 5) + j;
    int row = P_perm(k);
    int col = mb * 32 + (l & 31);
    float v = W[row * 128 + col];
    unsigned int u = __builtin_bit_cast(unsigned int, v);
    u = (u + 0x7fffu + ((u >> 16) & 1u)) >> 16;
    dst[idx] = (unsigned short)u;
}

// one full 128-col GEMM for 32 rows: acc[mb] = X @ W_mat (cols mb*32..mb*32+31)
__device__ __forceinline__ void gemm4(const short8* __restrict__ fragp, int lane, int mat,
                                      const short8 (&x)[8], f32x16 (&acc)[4]) {
#pragma unroll
    for (int mb = 0; mb < 4; ++mb) {
        f32x16 a = {0.f, 0.f, 0.f, 0.f, 0.f, 0.f, 0.f, 0.f,
                    0.f, 0.f, 0.f, 0.f, 0.f, 0.f, 0.f, 0.f};
#pragma unroll
        for (int c = 0; c < 8; ++c) {
            short8 wf = fragp[((mat * 4 + mb) * 8 + c) * 64 + lane];
            a = __builtin_amdgcn_mfma_f32_32x32x16_bf16(wf, x[c], a, 0, 0, 0);
        }
        acc[mb] = a;
    }
}

__launch_bounds__(256, 2)
__global__ void k_main(const float* __restrict__ em, const float* __restrict__ ed,
                       const unsigned short* __restrict__ frags,
                       const float* __restrict__ w2, float* __restrict__ out) {
    const int lane = threadIdx.x & 63;
    const int h = lane >> 5;
    const int n = lane & 31;
    const int wave = (int)((blockIdx.x * blockDim.x + threadIdx.x) >> 6);
    const long row = (long)wave * 32 + n;
    const float* emr = em + row * 128;
    const float* edr = ed + row * 128;
    const short8* fragp = (const short8*)frags;

    short8 em_bf[8], ed_bf[8], t1[8], t2[8];
    float s_mm = 0.f, s_dd = 0.f, s_md = 0.f, s_ab = 0.f;

    // load em/ed in slot order (lane h,n gets cols nb*32+q*8+4h+rr), reductions on the fly
#pragma unroll
    for (int i = 0; i < 16; ++i) {
        const int nb = i >> 2, q = i & 3;
        const int col = nb * 32 + q * 8 + 4 * h;
        float4 vm = *(const float4*)(emr + col);
        float4 vd = *(const float4*)(edr + col);
        s_mm += vm.x * vm.x + vm.y * vm.y + vm.z * vm.z + vm.w * vm.w;
        s_dd += vd.x * vd.x + vd.y * vd.y + vd.z * vd.z + vd.w * vd.w;
        s_md += vm.x * vd.x + vm.y * vd.y + vm.z * vd.z + vm.w * vd.w;
        s_ab += fabsf(vm.x - vd.x) + fabsf(vm.y - vd.y) + fabsf(vm.z - vd.z) + fabsf(vm.w - vd.w);
        const int cp = nb * 2 + (q >> 1);
        const int jb = (q & 1) * 4;
        em_bf[cp][jb + 0] = bf16rne(vm.x);
        em_bf[cp][jb + 1] = bf16rne(vm.y);
        em_bf[cp][jb + 2] = bf16rne(vm.z);
        em_bf[cp][jb + 3] = bf16rne(vm.w);
        ed_bf[cp][jb + 0] = bf16rne(vd.x);
        ed_bf[cp][jb + 1] = bf16rne(vd.y);
        ed_bf[cp][jb + 2] = bf16rne(vd.z);
        ed_bf[cp][jb + 3] = bf16rne(vd.w);
    }
    s_mm += __shfl_xor(s_mm, 32);
    s_dd += __shfl_xor(s_dd, 32);
    s_md += __shfl_xor(s_md, 32);
    s_ab += __shfl_xor(s_ab, 32);

    // adjacency closed form: pL = min(pL_cos, pL_manh), both [[a,b],[b,a]]
    const float m_ = s_ab;                       // manh off-diag >= 0, lrelu = id
    const float a3 = 1.f / (1.f + m_);
    const float b3 = m_ * a3;
    float cosv = s_md * rsqrtf((s_mm + 1e-8f) * (s_dd + 1e-8f));
    float cl = cosv < 0.f ? 0.01f * cosv : cosv; // leaky_relu 0.01
    const float a1n = 1.f / (1.f + cl);
    const float b1 = cl * a1n;
    const float pa = fminf(a1n, a3);
    const float pb = fminf(b1, b3);

    // u_m = pa*em+pb*ed, u_d = pb*em+pa*ed  (GCN linearity)
#pragma unroll
    for (int c = 0; c < 8; ++c)
#pragma unroll
        for (int j = 0; j < 8; ++j) {
            float fm = bf2f(em_bf[c][j]), fd = bf2f(ed_bf[c][j]);
            t1[c][j] = bf16rne(pa * fm + pb * fd);
            t2[c][j] = bf16rne(pb * fm + pa * fd);
        }

    f32x16 acc[4];

    // x1_m = relu(u_m@Wgcn)+em
    gemm4(fragp, lane, 0, t1, acc);
#pragma unroll
    for (int mb = 0; mb < 4; ++mb)
#pragma unroll
        for (int r = 0; r < 16; ++r) {
            const int c = mb * 2 + (r >> 3), j = r & 7;
            float g = acc[mb][r];
            g = g > 0.f ? g : 0.f;
            t1[c][j] = bf16rne(g + bf2f(em_bf[c][j]));
        }
    // x1_d = relu(u_d@Wgcn)+ed
    gemm4(fragp, lane, 0, t2, acc);
#pragma unroll
    for (int mb = 0; mb < 4; ++mb)
#pragma unroll
        for (int r = 0; r < 16; ++r) {
            const int c = mb * 2 + (r >> 3), j = r & 7;
            float g = acc[mb][r];
            g = g > 0.f ? g : 0.f;
            t2[c][j] = bf16rne(g + bf2f(ed_bf[c][j]));
        }

    const float isq = 0.08838834764831845f;      // 1/sqrt(128)

    // ---- m attention: t_m = x1_m@M_m ; logits ; mix ; mLA = mix@Wv_m ----
    gemm4(fragp, lane, 1, t1, acc);
    float l0 = 0.f, l1 = 0.f;
#pragma unroll
    for (int mb = 0; mb < 4; ++mb)
#pragma unroll
        for (int r = 0; r < 16; ++r) {
            const int c = mb * 2 + (r >> 3), j = r & 7;
            float tv = acc[mb][r];
            l0 += tv * bf2f(em_bf[c][j]);
            l1 += tv * bf2f(t1[c][j]);
        }
    l0 += __shfl_xor(l0, 32);
    l1 += __shfl_xor(l1, 32);
    l0 *= isq; l1 *= isq;
    {
        float mx = fmaxf(l0, l1);
        float e0 = __expf(l0 - mx), e1 = __expf(l1 - mx);
        float inv = 1.f / (e0 + e1);
        float aw0 = e0 * inv, aw1 = e1 * inv;
#pragma unroll
        for (int c = 0; c < 8; ++c)
#pragma unroll
            for (int j = 0; j < 8; ++j)
                t1[c][j] = bf16rne(aw0 * bf2f(em_bf[c][j]) + aw1 * bf2f(t1[c][j]));
    }
    gemm4(fragp, lane, 3, t1, acc);
#pragma unroll
    for (int mb = 0; mb < 4; ++mb)
#pragma unroll
        for (int r = 0; r < 16; ++r) {
            const int c = mb * 2 + (r >> 3), j = r & 7;
            em_bf[c][j] = bf16rne(acc[mb][r]);   // mLA (em dead)
        }

    // ---- d attention ----
    gemm4(fragp, lane, 2, t2, acc);
    float l0d = 0.f, l1d = 0.f;
#pragma unroll
    for (int mb = 0; mb < 4; ++mb)
#pragma unroll
        for (int r = 0; r < 16; ++r) {
            const int c = mb * 2 + (r >> 3), j = r & 7;
            float tv = acc[mb][r];
            l0d += tv * bf2f(ed_bf[c][j]);
            l1d += tv * bf2f(t2[c][j]);
        }
    l0d += __shfl_xor(l0d, 32);
    l1d += __shfl_xor(l1d, 32);
    l0d *= isq; l1d *= isq;
    {
        float mx = fmaxf(l0d, l1d);
        float e0 = __expf(l0d - mx), e1 = __expf(l1d - mx);
        float inv = 1.f / (e0 + e1);
        float aw0 = e0 * inv, aw1 = e1 * inv;
#pragma unroll
        for (int c = 0; c < 8; ++c)
#pragma unroll
            for (int j = 0; j < 8; ++j)
                t2[c][j] = bf16rne(aw0 * bf2f(ed_bf[c][j]) + aw1 * bf2f(t2[c][j]));
    }
    gemm4(fragp, lane, 4, t2, acc);              // dLA in acc

    // ne = mLA * dLA
#pragma unroll
    for (int mb = 0; mb < 4; ++mb)
#pragma unroll
        for (int r = 0; r < 16; ++r) {
            const int c = mb * 2 + (r >> 3), j = r & 7;
            t1[c][j] = bf16rne(bf2f(em_bf[c][j]) * acc[mb][r]);
        }
    // h = relu(ne@W1) ; pre = h . w2 ; out = sigmoid(pre)
    gemm4(fragp, lane, 5, t1, acc);
    float pre = 0.f;
#pragma unroll
    for (int i = 0; i < 16; ++i) {
        const int nb = i >> 2, q = i & 3;
        const int col = nb * 32 + q * 8 + 4 * h;
        float4 wv = *(const float4*)(w2 + col);
        float g0 = fmaxf(acc[nb][q * 4 + 0], 0.f);
        float g1 = fmaxf(acc[nb][q * 4 + 1], 0.f);
        float g2 = fmaxf(acc[nb][q * 4 + 2], 0.f);
        float g3 = fmaxf(acc[nb][q * 4 + 3], 0.f);
        pre += g0 * wv.x + g1 * wv.y + g2 * wv.z + g3 * wv.w;
    }
    pre += __shfl_xor(pre, 32);
    if (h == 0) out[row] = 1.f / (1.f + __expf(-pre));
}

extern "C" void kernel_launch(void* const* d_in, const int* in_sizes, int n_in,
                              void* d_out, int out_size, void* d_ws, size_t ws_size,
                              hipStream_t stream) {
    const float* em    = (const float*)d_in[0];
    const float* ed    = (const float*)d_in[1];
    const float* W_gcn = (const float*)d_in[2];
    const float* Wq_m  = (const float*)d_in[3];
    const float* Wk_m  = (const float*)d_in[4];
    const float* Wv_m  = (const float*)d_in[5];
    const float* Wq_d  = (const float*)d_in[6];
    const float* Wk_d  = (const float*)d_in[7];
    const float* Wv_d  = (const float*)d_in[8];
    const float* W1    = (const float*)d_in[9];
    const float* W2    = (const float*)d_in[10];
    float* out = (float*)d_out;

    float* M_m = (float*)d_ws;                         // 128*128 fp32
    float* M_d = M_m + 128 * 128;                      // 128*128 fp32
    unsigned short* frags = (unsigned short*)(M_d + 128 * 128);  // 6*16384 bf16

    const int B = in_sizes[0] / 128;                   // 262144

    hipLaunchKernelGGL(k_matmul_qkT, dim3(64), dim3(256), 0, stream, Wq_m, Wk_m, M_m);
    hipLaunchKernelGGL(k_matmul_qkT, dim3(64), dim3(256), 0, stream, Wq_d, Wk_d, M_d);
    hipLaunchKernelGGL(k_pack, dim3(384), dim3(256), 0, stream,
                       W_gcn, M_m, M_d, Wv_m, Wv_d, W1, frags);
    hipLaunchKernelGGL(k_main, dim3(B / 128), dim3(256), 0, stream,
                       em, ed, frags, W2, out);
}

// Round 2
// 678.304 us; speedup vs baseline: 1.1270x; 1.1270x over previous
//
#include <hip/hip_runtime.h>
#include <hip/hip_bf16.h>

// Fused kernel for MDI_2422361555492 on gfx950.
// Per row: pa,pb from 2x2 adjacency closed form; GCN via linearity
// (gm=em@W, gd=ed@W, combine with pa/pb in epilogue); attention via
// bilinear M=Wq@Wk^T; V-mix before projection; MLP head.
// MFMA mapping: C^T = W^T X^T with 32x32x16 bf16; X rows on lane&31 for both
// B-operand and C/D output; weight rows pre-permuted by P so GEMM outputs feed
// the next GEMM directly from registers (no LDS, no barriers).
// R1 lesson: per-mb fused epilogues keep acc at 16-32 VGPRs (was 64) and
// throttle weight-frag loads -> no scratch spill (R0 spilled ~1.5 GB).

typedef __attribute__((ext_vector_type(8))) short short8;
typedef __attribute__((ext_vector_type(16))) float f32x16;

__device__ __forceinline__ short bf16rne(float f) {
    unsigned int u = __builtin_bit_cast(unsigned int, f);
    u = (u + 0x7fffu + ((u >> 16) & 1u)) >> 16;
    return (short)u;
}
__device__ __forceinline__ float bf2f(short s) {
    unsigned int u = ((unsigned int)(unsigned short)s) << 16;
    return __builtin_bit_cast(float, u);
}

// Column-permutation induced by identifying GEMM-output slots with B-operand slots.
__host__ __device__ __forceinline__ int P_perm(int k) {
    int c = k >> 4, t = k & 15, h = t >> 3, j = t & 7;
    return ((c >> 1) << 5) | ((c & 1) << 4) | ((j >> 2) << 3) | (h << 2) | (j & 3);
}

// ---- prologue 1: M = Wq @ Wk^T  (128x128, fp32), Wk staged in padded LDS ----
__global__ void k_matmul_qkT(const float* __restrict__ Wq, const float* __restrict__ Wk,
                             float* __restrict__ M) {
    __shared__ float lds[128 * 129];
    for (int i = threadIdx.x; i < 16384; i += 256) {
        lds[(i >> 7) * 129 + (i & 127)] = Wk[i];
    }
    __syncthreads();
    int idx = blockIdx.x * 256 + threadIdx.x;          // 64 blocks x 256
    int a = idx >> 7, b = idx & 127;
    float s = 0.f;
#pragma unroll 8
    for (int c = 0; c < 128; ++c) s += Wq[a * 128 + c] * lds[b * 129 + c];
    M[idx] = s;
}

// ---- prologue 2: pack 6 matrices into P-permuted bf16 A-fragments ----
// layout: dst[(((mat*4+mb)*8 + c)*64 + lane)*8 + j]
//   value = bf16( W[P(16c + 8*(lane>>5) + j)][mb*32 + (lane&31)] )
__global__ void k_pack(const float* __restrict__ W0, const float* __restrict__ W1,
                       const float* __restrict__ W2, const float* __restrict__ W3,
                       const float* __restrict__ W4, const float* __restrict__ W5,
                       unsigned short* __restrict__ dst) {
    int idx = blockIdx.x * blockDim.x + threadIdx.x;   // 6*16384 threads
    int mat = idx >> 14;
    int r = idx & 16383;
    int mb = r >> 12;
    int c = (r >> 9) & 7;
    int l = (r >> 3) & 63;
    int j = r & 7;
    const float* W = mat == 0 ? W0 : mat == 1 ? W1 : mat == 2 ? W2
                   : mat == 3 ? W3 : mat == 4 ? W4 : W5;
    int k = 16 * c + 8 * (l >> 5) + j;
    int row = P_perm(k);
    int col = mb * 32 + (l & 31);
    float v = W[row * 128 + col];
    unsigned int u = __builtin_bit_cast(unsigned int, v);
    u = (u + 0x7fffu + ((u >> 16) & 1u)) >> 16;
    dst[idx] = (unsigned short)u;
}

// one 32-column block of X @ W_mat for 32 rows; consumed immediately by caller
__device__ __forceinline__ f32x16 gemm_mb(const short8* __restrict__ fragp, int lane,
                                          int mat, int mb, const short8 (&x)[8]) {
    f32x16 a = {0.f, 0.f, 0.f, 0.f, 0.f, 0.f, 0.f, 0.f,
                0.f, 0.f, 0.f, 0.f, 0.f, 0.f, 0.f, 0.f};
#pragma unroll
    for (int c = 0; c < 8; ++c) {
        short8 wf = fragp[((mat * 4 + mb) * 8 + c) * 64 + lane];
        a = __builtin_amdgcn_mfma_f32_32x32x16_bf16(wf, x[c], a, 0, 0, 0);
    }
    return a;
}

__launch_bounds__(256, 2)
__global__ void k_main(const float* __restrict__ em, const float* __restrict__ ed,
                       const unsigned short* __restrict__ frags,
                       const float* __restrict__ w2, float* __restrict__ out) {
    const int lane = threadIdx.x & 63;
    const int h = lane >> 5;
    const int n = lane & 31;
    const int wave = (int)((blockIdx.x * blockDim.x + threadIdx.x) >> 6);
    const long row = (long)wave * 32 + n;
    const float* emr = em + row * 128;
    const float* edr = ed + row * 128;
    const short8* fragp = (const short8*)frags;

    short8 em_bf[8], ed_bf[8], t1[8], t2[8];
    float s_mm = 0.f, s_dd = 0.f, s_md = 0.f, s_ab = 0.f;

    // load em/ed in slot order (lane h,n gets cols nb*32+q*8+4h+rr), reductions on the fly
#pragma unroll
    for (int i = 0; i < 16; ++i) {
        const int nb = i >> 2, q = i & 3;
        const int col = nb * 32 + q * 8 + 4 * h;
        float4 vm = *(const float4*)(emr + col);
        float4 vd = *(const float4*)(edr + col);
        s_mm += vm.x * vm.x + vm.y * vm.y + vm.z * vm.z + vm.w * vm.w;
        s_dd += vd.x * vd.x + vd.y * vd.y + vd.z * vd.z + vd.w * vd.w;
        s_md += vm.x * vd.x + vm.y * vd.y + vm.z * vd.z + vm.w * vd.w;
        s_ab += fabsf(vm.x - vd.x) + fabsf(vm.y - vd.y) + fabsf(vm.z - vd.z) + fabsf(vm.w - vd.w);
        const int cp = nb * 2 + (q >> 1);
        const int jb = (q & 1) * 4;
        em_bf[cp][jb + 0] = bf16rne(vm.x);
        em_bf[cp][jb + 1] = bf16rne(vm.y);
        em_bf[cp][jb + 2] = bf16rne(vm.z);
        em_bf[cp][jb + 3] = bf16rne(vm.w);
        ed_bf[cp][jb + 0] = bf16rne(vd.x);
        ed_bf[cp][jb + 1] = bf16rne(vd.y);
        ed_bf[cp][jb + 2] = bf16rne(vd.z);
        ed_bf[cp][jb + 3] = bf16rne(vd.w);
    }
    s_mm += __shfl_xor(s_mm, 32);
    s_dd += __shfl_xor(s_dd, 32);
    s_md += __shfl_xor(s_md, 32);
    s_ab += __shfl_xor(s_ab, 32);

    // adjacency closed form: pL = min(pL_cos, pL_manh), both [[a,b],[b,a]]
    const float m_ = s_ab;                       // manh off-diag >= 0, lrelu = id
    const float a3 = 1.f / (1.f + m_);
    const float b3 = m_ * a3;
    float cosv = s_md * rsqrtf((s_mm + 1e-8f) * (s_dd + 1e-8f));
    float cl = cosv < 0.f ? 0.01f * cosv : cosv; // leaky_relu 0.01
    const float a1n = 1.f / (1.f + cl);
    const float b1 = cl * a1n;
    const float pa = fminf(a1n, a3);
    const float pb = fminf(b1, b3);

    // ---- GCN via linearity: gm = em@W, gd = ed@W; combine in epilogue ----
    // x1_m = relu(pa*gm+pb*gd)+em -> t1 ; x1_d = relu(pb*gm+pa*gd)+ed -> t2
#pragma unroll
    for (int mb = 0; mb < 4; ++mb) {
        f32x16 gm = gemm_mb(fragp, lane, 0, mb, em_bf);
        f32x16 gd = gemm_mb(fragp, lane, 0, mb, ed_bf);
#pragma unroll
        for (int r = 0; r < 16; ++r) {
            const int c = mb * 2 + (r >> 3), j = r & 7;
            float vm = pa * gm[r] + pb * gd[r];
            float vd = pb * gm[r] + pa * gd[r];
            vm = vm > 0.f ? vm : 0.f;
            vd = vd > 0.f ? vd : 0.f;
            t1[c][j] = bf16rne(vm + bf2f(em_bf[c][j]));
            t2[c][j] = bf16rne(vd + bf2f(ed_bf[c][j]));
        }
    }

    const float isq = 0.08838834764831845f;      // 1/sqrt(128)

    // ---- m attention: t_m = x1_m@M_m ; logits ; mix ; mLA = mix@Wv_m ----
    float l0 = 0.f, l1 = 0.f;
#pragma unroll
    for (int mb = 0; mb < 4; ++mb) {
        f32x16 tv = gemm_mb(fragp, lane, 1, mb, t1);
#pragma unroll
        for (int r = 0; r < 16; ++r) {
            const int c = mb * 2 + (r >> 3), j = r & 7;
            l0 += tv[r] * bf2f(em_bf[c][j]);
            l1 += tv[r] * bf2f(t1[c][j]);
        }
    }
    l0 += __shfl_xor(l0, 32);
    l1 += __shfl_xor(l1, 32);
    l0 *= isq; l1 *= isq;
    {
        float mx = fmaxf(l0, l1);
        float e0 = __expf(l0 - mx), e1 = __expf(l1 - mx);
        float inv = 1.f / (e0 + e1);
        float aw0 = e0 * inv, aw1 = e1 * inv;
#pragma unroll
        for (int c = 0; c < 8; ++c)
#pragma unroll
            for (int j = 0; j < 8; ++j)
                t1[c][j] = bf16rne(aw0 * bf2f(em_bf[c][j]) + aw1 * bf2f(t1[c][j]));
    }
    // mLA -> em_bf (em dead after this point)
#pragma unroll
    for (int mb = 0; mb < 4; ++mb) {
        f32x16 v = gemm_mb(fragp, lane, 3, mb, t1);
#pragma unroll
        for (int r = 0; r < 16; ++r) {
            const int c = mb * 2 + (r >> 3), j = r & 7;
            em_bf[c][j] = bf16rne(v[r]);
        }
    }

    // ---- d attention ----
    float l0d = 0.f, l1d = 0.f;
#pragma unroll
    for (int mb = 0; mb < 4; ++mb) {
        f32x16 tv = gemm_mb(fragp, lane, 2, mb, t2);
#pragma unroll
        for (int r = 0; r < 16; ++r) {
            const int c = mb * 2 + (r >> 3), j = r & 7;
            l0d += tv[r] * bf2f(ed_bf[c][j]);
            l1d += tv[r] * bf2f(t2[c][j]);
        }
    }
    l0d += __shfl_xor(l0d, 32);
    l1d += __shfl_xor(l1d, 32);
    l0d *= isq; l1d *= isq;
    {
        float mx = fmaxf(l0d, l1d);
        float e0 = __expf(l0d - mx), e1 = __expf(l1d - mx);
        float inv = 1.f / (e0 + e1);
        float aw0 = e0 * inv, aw1 = e1 * inv;
#pragma unroll
        for (int c = 0; c < 8; ++c)
#pragma unroll
            for (int j = 0; j < 8; ++j)
                t2[c][j] = bf16rne(aw0 * bf2f(ed_bf[c][j]) + aw1 * bf2f(t2[c][j]));
    }
    // dLA fused with ne = mLA*dLA -> t1  (t1 dead, t2 is gemm input)
#pragma unroll
    for (int mb = 0; mb < 4; ++mb) {
        f32x16 v = gemm_mb(fragp, lane, 4, mb, t2);
#pragma unroll
        for (int r = 0; r < 16; ++r) {
            const int c = mb * 2 + (r >> 3), j = r & 7;
            t1[c][j] = bf16rne(bf2f(em_bf[c][j]) * v[r]);
        }
    }
    // h = relu(ne@W1) ; pre = h . w2 ; out = sigmoid(pre)
    float pre = 0.f;
#pragma unroll
    for (int mb = 0; mb < 4; ++mb) {
        f32x16 v = gemm_mb(fragp, lane, 5, mb, t1);
#pragma unroll
        for (int q = 0; q < 4; ++q) {
            const int col = mb * 32 + q * 8 + 4 * h;
            float4 wv = *(const float4*)(w2 + col);
            pre += fmaxf(v[q * 4 + 0], 0.f) * wv.x;
            pre += fmaxf(v[q * 4 + 1], 0.f) * wv.y;
            pre += fmaxf(v[q * 4 + 2], 0.f) * wv.z;
            pre += fmaxf(v[q * 4 + 3], 0.f) * wv.w;
        }
    }
    pre += __shfl_xor(pre, 32);
    if (h == 0) out[row] = 1.f / (1.f + __expf(-pre));
}

extern "C" void kernel_launch(void* const* d_in, const int* in_sizes, int n_in,
                              void* d_out, int out_size, void* d_ws, size_t ws_size,
                              hipStream_t stream) {
    const float* em    = (const float*)d_in[0];
    const float* ed    = (const float*)d_in[1];
    const float* W_gcn = (const float*)d_in[2];
    const float* Wq_m  = (const float*)d_in[3];
    const float* Wk_m  = (const float*)d_in[4];
    const float* Wv_m  = (const float*)d_in[5];
    const float* Wq_d  = (const float*)d_in[6];
    const float* Wk_d  = (const float*)d_in[7];
    const float* Wv_d  = (const float*)d_in[8];
    const float* W1    = (const float*)d_in[9];
    const float* W2    = (const float*)d_in[10];
    float* out = (float*)d_out;

    float* M_m = (float*)d_ws;                         // 128*128 fp32
    float* M_d = M_m + 128 * 128;                      // 128*128 fp32
    unsigned short* frags = (unsigned short*)(M_d + 128 * 128);  // 6*16384 bf16

    const int B = in_sizes[0] / 128;                   // 262144

    hipLaunchKernelGGL(k_matmul_qkT, dim3(64), dim3(256), 0, stream, Wq_m, Wk_m, M_m);
    hipLaunchKernelGGL(k_matmul_qkT, dim3(64), dim3(256), 0, stream, Wq_d, Wk_d, M_d);
    hipLaunchKernelGGL(k_pack, dim3(384), dim3(256), 0, stream,
                       W_gcn, M_m, M_d, Wv_m, Wv_d, W1, frags);
    hipLaunchKernelGGL(k_main, dim3(B / 128), dim3(256), 0, stream,
                       em, ed, frags, W2, out);
}

// Round 3
// 528.925 us; speedup vs baseline: 1.4453x; 1.2824x over previous
//
#include <hip/hip_runtime.h>
#include <hip/hip_bf16.h>

// Fused kernel for MDI_2422361555492 on gfx950.
// Per row: pa,pb from 2x2 adjacency closed form; GCN via linearity
// (gm=em@W, gd=ed@W, combine with pa/pb in epilogue); attention via
// bilinear M=Wq@Wk^T; V-mix before projection; MLP head.
// MFMA mapping: C^T = W^T X^T with 32x32x16 bf16; X rows on lane&31 for both
// B-operand and C/D output; weight rows pre-permuted by P so GEMM outputs feed
// the next GEMM directly from registers.
// R1 lesson: fused per-mb epilogues (acc 16-32 regs, not 64).
// R2 lesson: still spilled ~80 regs (WRITE_SIZE 652 MB). Arch-VGPR partition
// is ~128; four 32-reg bf16 arrays + hoisted frags exceed it. Fix: park
// em_bf/ed_bf in LDS (thread-private, tid-major 16B stride = uniform banks,
// no barriers), and share one frag load across both GCN MFMAs.

typedef __attribute__((ext_vector_type(8))) short short8;
typedef __attribute__((ext_vector_type(16))) float f32x16;

__device__ __forceinline__ short bf16rne(float f) {
    unsigned int u = __builtin_bit_cast(unsigned int, f);
    u = (u + 0x7fffu + ((u >> 16) & 1u)) >> 16;
    return (short)u;
}
__device__ __forceinline__ float bf2f(short s) {
    unsigned int u = ((unsigned int)(unsigned short)s) << 16;
    return __builtin_bit_cast(float, u);
}

// Column-permutation induced by identifying GEMM-output slots with B-operand slots.
__host__ __device__ __forceinline__ int P_perm(int k) {
    int c = k >> 4, t = k & 15, h = t >> 3, j = t & 7;
    return ((c >> 1) << 5) | ((c & 1) << 4) | ((j >> 2) << 3) | (h << 2) | (j & 3);
}

// ---- prologue 1: M = Wq @ Wk^T  (128x128, fp32), Wk staged in padded LDS ----
__global__ void k_matmul_qkT(const float* __restrict__ Wq, const float* __restrict__ Wk,
                             float* __restrict__ M) {
    __shared__ float lds[128 * 129];
    for (int i = threadIdx.x; i < 16384; i += 256) {
        lds[(i >> 7) * 129 + (i & 127)] = Wk[i];
    }
    __syncthreads();
    int idx = blockIdx.x * 256 + threadIdx.x;          // 64 blocks x 256
    int a = idx >> 7, b = idx & 127;
    float s = 0.f;
#pragma unroll 8
    for (int c = 0; c < 128; ++c) s += Wq[a * 128 + c] * lds[b * 129 + c];
    M[idx] = s;
}

// ---- prologue 2: pack 6 matrices into P-permuted bf16 A-fragments ----
// layout: dst[(((mat*4+mb)*8 + c)*64 + lane)*8 + j]
//   value = bf16( W[P(16c + 8*(lane>>5) + j)][mb*32 + (lane&31)] )
__global__ void k_pack(const float* __restrict__ W0, const float* __restrict__ W1,
                       const float* __restrict__ W2, const float* __restrict__ W3,
                       const float* __restrict__ W4, const float* __restrict__ W5,
                       unsigned short* __restrict__ dst) {
    int idx = blockIdx.x * blockDim.x + threadIdx.x;   // 6*16384 threads
    int mat = idx >> 14;
    int r = idx & 16383;
    int mb = r >> 12;
    int c = (r >> 9) & 7;
    int l = (r >> 3) & 63;
    int j = r & 7;
    const float* W = mat == 0 ? W0 : mat == 1 ? W1 : mat == 2 ? W2
                   : mat == 3 ? W3 : mat == 4 ? W4 : W5;
    int k = 16 * c + 8 * (l >> 5) + j;
    int row = P_perm(k);
    int col = mb * 32 + (l & 31);
    float v = W[row * 128 + col];
    unsigned int u = __builtin_bit_cast(unsigned int, v);
    u = (u + 0x7fffu + ((u >> 16) & 1u)) >> 16;
    dst[idx] = (unsigned short)u;
}

// one 32-column block of X @ W_mat for 32 rows; consumed immediately by caller
__device__ __forceinline__ f32x16 gemm_mb(const short8* __restrict__ fragp, int lane,
                                          int mat, int mb, const short8 (&x)[8]) {
    f32x16 a = {0.f, 0.f, 0.f, 0.f, 0.f, 0.f, 0.f, 0.f,
                0.f, 0.f, 0.f, 0.f, 0.f, 0.f, 0.f, 0.f};
#pragma unroll
    for (int c = 0; c < 8; ++c) {
        short8 wf = fragp[((mat * 4 + mb) * 8 + c) * 64 + lane];
        a = __builtin_amdgcn_mfma_f32_32x32x16_bf16(wf, x[c], a, 0, 0, 0);
    }
    return a;
}

__launch_bounds__(256, 2)
__global__ void k_main(const float* __restrict__ em, const float* __restrict__ ed,
                       const unsigned short* __restrict__ frags,
                       const float* __restrict__ w2, float* __restrict__ out) {
    __shared__ short8 S_em[8][256];                    // 32 KB, thread-private slots
    __shared__ short8 S_ed[8][256];                    // 32 KB
    const int tid = threadIdx.x;
    const int lane = tid & 63;
    const int h = lane >> 5;
    const int n = lane & 31;
    const int wave = (int)((blockIdx.x * blockDim.x + tid) >> 6);
    const long row = (long)wave * 32 + n;
    const float* emr = em + row * 128;
    const float* edr = ed + row * 128;
    const short8* fragp = (const short8*)frags;

    short8 t1[8], t2[8];
    float s_mm = 0.f, s_dd = 0.f, s_md = 0.f, s_ab = 0.f;

    // load em/ed in slot order; reductions on the fly; park bf16 slots in LDS
#pragma unroll
    for (int cp = 0; cp < 8; ++cp) {
        const int nb = cp >> 1;
        short8 e8m, e8d;
#pragma unroll
        for (int half = 0; half < 2; ++half) {
            const int q = (cp & 1) * 2 + half;
            const int col = nb * 32 + q * 8 + 4 * h;
            float4 vm = *(const float4*)(emr + col);
            float4 vd = *(const float4*)(edr + col);
            s_mm += vm.x * vm.x + vm.y * vm.y + vm.z * vm.z + vm.w * vm.w;
            s_dd += vd.x * vd.x + vd.y * vd.y + vd.z * vd.z + vd.w * vd.w;
            s_md += vm.x * vd.x + vm.y * vd.y + vm.z * vd.z + vm.w * vd.w;
            s_ab += fabsf(vm.x - vd.x) + fabsf(vm.y - vd.y) + fabsf(vm.z - vd.z) + fabsf(vm.w - vd.w);
            const int jb = half * 4;
            e8m[jb + 0] = bf16rne(vm.x);
            e8m[jb + 1] = bf16rne(vm.y);
            e8m[jb + 2] = bf16rne(vm.z);
            e8m[jb + 3] = bf16rne(vm.w);
            e8d[jb + 0] = bf16rne(vd.x);
            e8d[jb + 1] = bf16rne(vd.y);
            e8d[jb + 2] = bf16rne(vd.z);
            e8d[jb + 3] = bf16rne(vd.w);
        }
        S_em[cp][tid] = e8m;
        S_ed[cp][tid] = e8d;
        t1[cp] = e8m;                                  // keep for GCN gemm input
        t2[cp] = e8d;
    }
    s_mm += __shfl_xor(s_mm, 32);
    s_dd += __shfl_xor(s_dd, 32);
    s_md += __shfl_xor(s_md, 32);
    s_ab += __shfl_xor(s_ab, 32);

    // adjacency closed form: pL = min(pL_cos, pL_manh), both [[a,b],[b,a]]
    const float m_ = s_ab;                             // manh off-diag >= 0, lrelu = id
    const float a3 = 1.f / (1.f + m_);
    const float b3 = m_ * a3;
    float cosv = s_md * rsqrtf((s_mm + 1e-8f) * (s_dd + 1e-8f));
    float cl = cosv < 0.f ? 0.01f * cosv : cosv;       // leaky_relu 0.01
    const float a1n = 1.f / (1.f + cl);
    const float b1 = cl * a1n;
    const float pa = fminf(a1n, a3);
    const float pb = fminf(b1, b3);

    // ---- GCN: gm = em@W, gd = ed@W with one frag load per MFMA pair ----
    // x1_m = relu(pa*gm+pb*gd)+em -> t1 ; x1_d = relu(pb*gm+pa*gd)+ed -> t2
#pragma unroll
    for (int mb = 0; mb < 4; ++mb) {
        f32x16 gm = {0.f, 0.f, 0.f, 0.f, 0.f, 0.f, 0.f, 0.f,
                     0.f, 0.f, 0.f, 0.f, 0.f, 0.f, 0.f, 0.f};
        f32x16 gd = gm;
#pragma unroll
        for (int c = 0; c < 8; ++c) {
            short8 wf = fragp[((0 * 4 + mb) * 8 + c) * 64 + lane];
            gm = __builtin_amdgcn_mfma_f32_32x32x16_bf16(wf, t1[c], gm, 0, 0, 0);
            gd = __builtin_amdgcn_mfma_f32_32x32x16_bf16(wf, t2[c], gd, 0, 0, 0);
        }
#pragma unroll
        for (int r = 0; r < 16; ++r) {
            const int c = mb * 2 + (r >> 3), j = r & 7;
            float vm = pa * gm[r] + pb * gd[r];
            float vd = pb * gm[r] + pa * gd[r];
            vm = vm > 0.f ? vm : 0.f;
            vd = vd > 0.f ? vd : 0.f;
            // note: t1[c] for c<mb*2+... is being rewritten only at slots already
            // consumed by this mb's gemm? NOT true for c -- so read originals from LDS
            short8 e8m = S_em[c][tid];
            short8 e8d = S_ed[c][tid];
            t1[c][j] = bf16rne(vm + bf2f(e8m[j]));
            t2[c][j] = bf16rne(vd + bf2f(e8d[j]));
        }
    }

    const float isq = 0.08838834764831845f;            // 1/sqrt(128)

    // ---- m attention: t_m = x1_m@M_m ; logits ; mix ; mLA = mix@Wv_m ----
    float l0 = 0.f, l1 = 0.f;
#pragma unroll
    for (int mb = 0; mb < 4; ++mb) {
        f32x16 tv = gemm_mb(fragp, lane, 1, mb, t1);
#pragma unroll
        for (int r = 0; r < 16; ++r) {
            const int c = mb * 2 + (r >> 3), j = r & 7;
            short8 e8m = S_em[c][tid];
            l0 += tv[r] * bf2f(e8m[j]);
            l1 += tv[r] * bf2f(t1[c][j]);
        }
    }
    l0 += __shfl_xor(l0, 32);
    l1 += __shfl_xor(l1, 32);
    l0 *= isq; l1 *= isq;
    {
        float mx = fmaxf(l0, l1);
        float e0 = __expf(l0 - mx), e1 = __expf(l1 - mx);
        float inv = 1.f / (e0 + e1);
        float aw0 = e0 * inv, aw1 = e1 * inv;
#pragma unroll
        for (int c = 0; c < 8; ++c) {
            short8 e8m = S_em[c][tid];
#pragma unroll
            for (int j = 0; j < 8; ++j)
                t1[c][j] = bf16rne(aw0 * bf2f(e8m[j]) + aw1 * bf2f(t1[c][j]));
        }
    }
    // mLA -> S_em (em dead after this point)
#pragma unroll
    for (int mb = 0; mb < 4; ++mb) {
        f32x16 v = gemm_mb(fragp, lane, 3, mb, t1);
#pragma unroll
        for (int hh = 0; hh < 2; ++hh) {
            const int c = mb * 2 + hh;
            short8 o;
#pragma unroll
            for (int j = 0; j < 8; ++j) o[j] = bf16rne(v[hh * 8 + j]);
            S_em[c][tid] = o;
        }
    }

    // ---- d attention ----
    float l0d = 0.f, l1d = 0.f;
#pragma unroll
    for (int mb = 0; mb < 4; ++mb) {
        f32x16 tv = gemm_mb(fragp, lane, 2, mb, t2);
#pragma unroll
        for (int r = 0; r < 16; ++r) {
            const int c = mb * 2 + (r >> 3), j = r & 7;
            short8 e8d = S_ed[c][tid];
            l0d += tv[r] * bf2f(e8d[j]);
            l1d += tv[r] * bf2f(t2[c][j]);
        }
    }
    l0d += __shfl_xor(l0d, 32);
    l1d += __shfl_xor(l1d, 32);
    l0d *= isq; l1d *= isq;
    {
        float mx = fmaxf(l0d, l1d);
        float e0 = __expf(l0d - mx), e1 = __expf(l1d - mx);
        float inv = 1.f / (e0 + e1);
        float aw0 = e0 * inv, aw1 = e1 * inv;
#pragma unroll
        for (int c = 0; c < 8; ++c) {
            short8 e8d = S_ed[c][tid];
#pragma unroll
            for (int j = 0; j < 8; ++j)
                t2[c][j] = bf16rne(aw0 * bf2f(e8d[j]) + aw1 * bf2f(t2[c][j]));
        }
    }
    // dLA fused with ne = mLA*dLA -> t1  (t1 dead, t2 is gemm input)
#pragma unroll
    for (int mb = 0; mb < 4; ++mb) {
        f32x16 v = gemm_mb(fragp, lane, 4, mb, t2);
#pragma unroll
        for (int r = 0; r < 16; ++r) {
            const int c = mb * 2 + (r >> 3), j = r & 7;
            short8 mla = S_em[c][tid];
            t1[c][j] = bf16rne(bf2f(mla[j]) * v[r]);
        }
    }
    // h = relu(ne@W1) ; pre = h . w2 ; out = sigmoid(pre)
    float pre = 0.f;
#pragma unroll
    for (int mb = 0; mb < 4; ++mb) {
        f32x16 v = gemm_mb(fragp, lane, 5, mb, t1);
#pragma unroll
        for (int q = 0; q < 4; ++q) {
            const int col = mb * 32 + q * 8 + 4 * h;
            float4 wv = *(const float4*)(w2 + col);
            pre += fmaxf(v[q * 4 + 0], 0.f) * wv.x;
            pre += fmaxf(v[q * 4 + 1], 0.f) * wv.y;
            pre += fmaxf(v[q * 4 + 2], 0.f) * wv.z;
            pre += fmaxf(v[q * 4 + 3], 0.f) * wv.w;
        }
    }
    pre += __shfl_xor(pre, 32);
    if (h == 0) out[row] = 1.f / (1.f + __expf(-pre));
}

extern "C" void kernel_launch(void* const* d_in, const int* in_sizes, int n_in,
                              void* d_out, int out_size, void* d_ws, size_t ws_size,
                              hipStream_t stream) {
    const float* em    = (const float*)d_in[0];
    const float* ed    = (const float*)d_in[1];
    const float* W_gcn = (const float*)d_in[2];
    const float* Wq_m  = (const float*)d_in[3];
    const float* Wk_m  = (const float*)d_in[4];
    const float* Wv_m  = (const float*)d_in[5];
    const float* Wq_d  = (const float*)d_in[6];
    const float* Wk_d  = (const float*)d_in[7];
    const float* Wv_d  = (const float*)d_in[8];
    const float* W1    = (const float*)d_in[9];
    const float* W2    = (const float*)d_in[10];
    float* out = (float*)d_out;

    float* M_m = (float*)d_ws;                         // 128*128 fp32
    float* M_d = M_m + 128 * 128;                      // 128*128 fp32
    unsigned short* frags = (unsigned short*)(M_d + 128 * 128);  // 6*16384 bf16

    const int B = in_sizes[0] / 128;                   // 262144

    hipLaunchKernelGGL(k_matmul_qkT, dim3(64), dim3(256), 0, stream, Wq_m, Wk_m, M_m);
    hipLaunchKernelGGL(k_matmul_qkT, dim3(64), dim3(256), 0, stream, Wq_d, Wk_d, M_d);
    hipLaunchKernelGGL(k_pack, dim3(384), dim3(256), 0, stream,
                       W_gcn, M_m, M_d, Wv_m, Wv_d, W1, frags);
    hipLaunchKernelGGL(k_main, dim3(B / 128), dim3(256), 0, stream,
                       em, ed, frags, W2, out);
}